// Round 1
// baseline (193.001 us; speedup 1.0000x reference)
//
#include <hip/hip_runtime.h>

#define NPTS 8192
#define BATCH 64
#define TEXTD 512
#define LATENT 128
#define NEMB 512

__device__ __forceinline__ unsigned mono(float f) {
    unsigned u = __float_as_uint(f);
    return (u & 0x80000000u) ? ~u : (u | 0x80000000u);
}
__device__ __forceinline__ float unmono(unsigned k) {
    return __uint_as_float((k & 0x80000000u) ? (k & 0x7fffffffu) : ~k);
}

// keys := 0 (== -inf in monotone-uint space), W2T[j][k] = W2[k][j]
__global__ void k0_init(unsigned* __restrict__ keys, const float* __restrict__ W2,
                        float* __restrict__ W2T) {
    int idx = blockIdx.x * 256 + threadIdx.x;
    if (idx < 8192) {
        keys[idx] = 0u;
        int k = idx >> 7, j = idx & 127;
        W2T[j * 64 + k] = W2[idx];
    }
}

// One wave = 64 consecutive points of one batch. Lane-private h[64] in VGPRs,
// W2T rows are uniform -> scalar loads; butterfly max across the wave's 64
// points; one coalesced atomicMax per (b, feature).
__global__ __launch_bounds__(256) void k1_pointfeat(
    const float* __restrict__ x, const float* __restrict__ s,
    const float* __restrict__ W1, const float* __restrict__ b1,
    const float* __restrict__ W2T, const float* __restrict__ b2,
    unsigned* __restrict__ keys)
{
    const int tid  = threadIdx.x;
    const int lane = tid & 63;
    const int wid  = tid >> 6;
    const int tile = blockIdx.x * 4 + wid;     // 8192 tiles of 64 points
    const int gp   = tile * 64 + lane;         // global point index
    const int b    = gp >> 13;                 // batch (8192 pts/batch)

    const float px = x[(size_t)gp * 3 + 0];
    const float py = x[(size_t)gp * 3 + 1];
    const float pz = x[(size_t)gp * 3 + 2];
    const float pw = s[gp];

    float h[64];
    #pragma unroll
    for (int k = 0; k < 64; ++k) {
        float a = fmaf(px, W1[k],
                  fmaf(py, W1[64 + k],
                  fmaf(pz, W1[128 + k],
                  fmaf(pw, W1[192 + k], b1[k]))));
        h[k] = a > 0.f ? a : 0.f;
    }

    #pragma unroll
    for (int jh = 0; jh < 2; ++jh) {
        float keep = 0.f;
        #pragma unroll 1
        for (int jj = 0; jj < 64; ++jj) {
            const int f = jh * 64 + jj;
            const float* __restrict__ w = W2T + f * 64;  // uniform -> s_load
            float acc = b2[f];
            #pragma unroll
            for (int k = 0; k < 64; ++k) acc = fmaf(h[k], w[k], acc);
            // max over the wave's 64 points
            float m = acc;
            #pragma unroll
            for (int d = 1; d < 64; d <<= 1) m = fmaxf(m, __shfl_xor(m, d, 64));
            keep = (lane == jj) ? m : keep;
        }
        atomicMax(&keys[b * 128 + jh * 64 + lane], mono(keep));
    }
}

// One block per batch: head MLP + VQ.
__global__ __launch_bounds__(512) void k2_head(
    const unsigned* __restrict__ keys, const float* __restrict__ e,
    const float* __restrict__ W3, const float* __restrict__ b3,
    const float* __restrict__ W4, const float* __restrict__ b4,
    const float* __restrict__ cb, float* __restrict__ out)
{
    const int b = blockIdx.x, tid = threadIdx.x;
    __shared__ float comb[640];
    __shared__ float psum[512];
    __shared__ float hid[256];
    __shared__ float ze[128];
    __shared__ float red_d[512];
    __shared__ int   red_i[512];
    __shared__ float zzs;

    if (tid < 128) comb[tid] = unmono(keys[b * 128 + tid]);
    comb[128 + tid] = e[b * TEXTD + tid];   // tid < 512 covers all
    __syncthreads();

    // hidden = relu(comb @ W3 + b3), i-range split 2 ways
    {
        const int u = tid & 255, part = tid >> 8;
        float a = part ? 0.f : b3[u];
        const int i0 = part * 320;
        for (int i = i0; i < i0 + 320; ++i) a = fmaf(comb[i], W3[i * 256 + u], a);
        psum[part * 256 + u] = a;
    }
    __syncthreads();
    if (tid < 256) {
        float hv = psum[tid] + psum[256 + tid];
        hid[tid] = hv > 0.f ? hv : 0.f;
    }
    __syncthreads();

    // z_e = hid @ W4 + b4
    if (tid < 128) {
        float a = b4[tid];
        for (int i = 0; i < 256; ++i) a = fmaf(hid[i], W4[i * 128 + tid], a);
        ze[tid] = a;
        out[8192 + b * 128 + tid] = a;      // z_e output
    }
    __syncthreads();

    // zz = sum(z_e^2), wave 0
    if (tid < 64) {
        float t = ze[tid] * ze[tid] + ze[tid + 64] * ze[tid + 64];
        #pragma unroll
        for (int d = 1; d < 64; d <<= 1) t += __shfl_xor(t, d, 64);
        if (tid == 0) zzs = t;
    }
    __syncthreads();

    // dists: one code per thread
    {
        float dot = 0.f, cc = 0.f;
        const float* __restrict__ cp = cb + (size_t)tid * 128;
        #pragma unroll 8
        for (int k = 0; k < 128; ++k) {
            float v = cp[k];
            dot = fmaf(ze[k], v, dot);
            cc  = fmaf(v, v, cc);
        }
        red_d[tid] = zzs - 2.f * dot + cc;
        red_i[tid] = tid;
    }
    __syncthreads();

    // argmin (tie -> lowest index, = np.argmin)
    for (int sft = 256; sft >= 1; sft >>= 1) {
        if (tid < sft) {
            float da = red_d[tid], db = red_d[tid + sft];
            int   ia = red_i[tid], ib = red_i[tid + sft];
            if (db < da || (db == da && ib < ia)) { red_d[tid] = db; red_i[tid] = ib; }
        }
        __syncthreads();
    }
    const int bc = red_i[0];

    if (tid < 128) {
        float zq  = cb[(size_t)bc * 128 + tid];
        float zev = ze[tid];
        out[b * 128 + tid] = zev + (zq - zev);  // z_q_st
    }
    if (tid == 0) out[16386 + b] = (float)bc;   // index as float
}

// Deterministic single-block loss reduction.
__global__ __launch_bounds__(256) void k3_loss(const float* __restrict__ cb,
                                               float* __restrict__ out)
{
    const int tid = threadIdx.x;
    __shared__ float red[256];
    float p = 0.f;
    for (int i = tid; i < 8192; i += 256) {
        const int b = i >> 7, k = i & 127;
        const int idx = (int)out[16386 + b];
        float d = cb[(size_t)idx * 128 + k] - out[8192 + i];
        p = fmaf(d, d, p);
    }
    red[tid] = p;
    __syncthreads();
    for (int sft = 128; sft >= 1; sft >>= 1) {
        if (tid < sft) red[tid] += red[tid + sft];
        __syncthreads();
    }
    if (tid == 0) {
        float m = red[0] / 8192.f;
        out[16384] = m;   // codebook_loss
        out[16385] = m;   // commitment_loss (identical numerically)
    }
}

extern "C" void kernel_launch(void* const* d_in, const int* in_sizes, int n_in,
                              void* d_out, int out_size, void* d_ws, size_t ws_size,
                              hipStream_t stream) {
    const float* x  = (const float*)d_in[0];
    const float* s  = (const float*)d_in[1];
    const float* e  = (const float*)d_in[2];
    const float* W1 = (const float*)d_in[3];
    const float* b1 = (const float*)d_in[4];
    const float* W2 = (const float*)d_in[5];
    const float* b2 = (const float*)d_in[6];
    const float* W3 = (const float*)d_in[7];
    const float* b3 = (const float*)d_in[8];
    const float* W4 = (const float*)d_in[9];
    const float* b4 = (const float*)d_in[10];
    const float* cb = (const float*)d_in[11];
    float* out = (float*)d_out;

    unsigned* keys = (unsigned*)d_ws;                 // 8192 u32
    float*    W2T  = (float*)d_ws + 8192;             // 8192 f32

    k0_init<<<32, 256, 0, stream>>>(keys, W2, W2T);
    k1_pointfeat<<<2048, 256, 0, stream>>>(x, s, W1, b1, W2T, b2, keys);
    k2_head<<<64, 512, 0, stream>>>(keys, e, W3, b3, W4, b4, cb, out);
    k3_loss<<<1, 256, 0, stream>>>(cb, out);
}

// Round 2
// 181.264 us; speedup vs baseline: 1.0648x; 1.0648x over previous
//
#include <hip/hip_runtime.h>

#define TEXTD 512

__device__ __forceinline__ unsigned mono(float f) {
    unsigned u = __float_as_uint(f);
    return (u & 0x80000000u) ? ~u : (u | 0x80000000u);
}
__device__ __forceinline__ float unmono(unsigned k) {
    return __uint_as_float((k & 0x80000000u) ? (k & 0x7fffffffu) : ~k);
}

// keys := 0 (== -inf in monotone-uint space)
__global__ void k0_init(unsigned* __restrict__ keys) {
    int idx = blockIdx.x * 256 + threadIdx.x;
    if (idx < 8192) keys[idx] = 0u;
}

// One wave = 64 consecutive points of one batch (task). Lane = point.
// h[64] and acc[32] register-resident; W2 read at wave-uniform addresses
// (s_load broadcast). Per-tile max-reduce via swizzled LDS transpose.
// b2 is folded into k2 (max(x+b) = max(x)+b).
__global__ __launch_bounds__(256) void k1_pointfeat(
    const float* __restrict__ x, const float* __restrict__ s,
    const float* __restrict__ W1, const float* __restrict__ b1,
    const float* __restrict__ W2, unsigned* __restrict__ keys)
{
    __shared__ float red[4][64][32];            // 32 KB, per-wave slices
    const int tid  = threadIdx.x;
    const int lane = tid & 63;
    const int wid  = tid >> 6;
    const int task = blockIdx.x * 4 + wid;      // 8192 tasks of 64 points
    const int gp   = task * 64 + lane;
    const int b    = gp >> 13;                  // 8192 pts per batch

    const float px = x[(size_t)gp * 3 + 0];
    const float py = x[(size_t)gp * 3 + 1];
    const float pz = x[(size_t)gp * 3 + 2];
    const float pw = s[gp];

    float h[64];
    #pragma unroll
    for (int k = 0; k < 64; ++k) {
        float a = fmaf(px, W1[k],
                  fmaf(py, W1[64 + k],
                  fmaf(pz, W1[128 + k],
                  fmaf(pw, W1[192 + k], b1[k]))));
        h[k] = a > 0.f ? a : 0.f;
    }

    float (*myred)[32] = red[wid];
    const int c    = lane & 31;   // logical feature column this lane reduces
    const int half = lane >> 5;   // 0: points 0..31, 1: points 32..63

    #pragma unroll 1
    for (int t = 0; t < 4; ++t) {
        float acc[32];
        #pragma unroll
        for (int f = 0; f < 32; ++f) acc[f] = 0.f;

        const float* __restrict__ Wt = W2 + t * 32;   // uniform -> s_load
        #pragma unroll
        for (int k = 0; k < 64; ++k) {
            const float hk = h[k];
            #pragma unroll
            for (int f = 0; f < 32; ++f)
                acc[f] = fmaf(hk, Wt[k * 128 + f], acc[f]);
        }

        // XOR-swizzled transpose: write [lane][f^(lane&31)] -> bank-perm, free
        #pragma unroll
        for (int f = 0; f < 32; ++f)
            myred[lane][f ^ (lane & 31)] = acc[f];

        // read logical feature c of point pp at [pp][c^(pp&31)] -> bank-perm
        float m = -3.402823e38f;
        #pragma unroll
        for (int p = 0; p < 32; ++p) {
            const int pp = half * 32 + p;
            m = fmaxf(m, myred[pp][c ^ (pp & 31)]);
        }
        m = fmaxf(m, __shfl_xor(m, 32, 64));
        if (lane < 32) atomicMax(&keys[b * 128 + t * 32 + lane], mono(m));
    }
}

// One block per batch: head MLP + VQ. Adds the folded-out b2.
__global__ __launch_bounds__(512) void k2_head(
    const unsigned* __restrict__ keys, const float* __restrict__ b2,
    const float* __restrict__ e,
    const float* __restrict__ W3, const float* __restrict__ b3,
    const float* __restrict__ W4, const float* __restrict__ b4,
    const float* __restrict__ cb, float* __restrict__ out)
{
    const int b = blockIdx.x, tid = threadIdx.x;
    __shared__ float comb[640];
    __shared__ float psum[512];
    __shared__ float hid[256];
    __shared__ float ze[128];
    __shared__ float red_d[512];
    __shared__ int   red_i[512];
    __shared__ float zzs;

    if (tid < 128) comb[tid] = unmono(keys[b * 128 + tid]) + b2[tid];
    comb[128 + tid] = e[b * TEXTD + tid];   // tid < 512 covers all
    __syncthreads();

    // hidden = relu(comb @ W3 + b3), i-range split 2 ways
    {
        const int u = tid & 255, part = tid >> 8;
        float a = part ? 0.f : b3[u];
        const int i0 = part * 320;
        for (int i = i0; i < i0 + 320; ++i) a = fmaf(comb[i], W3[i * 256 + u], a);
        psum[part * 256 + u] = a;
    }
    __syncthreads();
    if (tid < 256) {
        float hv = psum[tid] + psum[256 + tid];
        hid[tid] = hv > 0.f ? hv : 0.f;
    }
    __syncthreads();

    // z_e = hid @ W4 + b4
    if (tid < 128) {
        float a = b4[tid];
        for (int i = 0; i < 256; ++i) a = fmaf(hid[i], W4[i * 128 + tid], a);
        ze[tid] = a;
        out[8192 + b * 128 + tid] = a;      // z_e output
    }
    __syncthreads();

    // zz = sum(z_e^2), wave 0
    if (tid < 64) {
        float t = ze[tid] * ze[tid] + ze[tid + 64] * ze[tid + 64];
        #pragma unroll
        for (int d = 1; d < 64; d <<= 1) t += __shfl_xor(t, d, 64);
        if (tid == 0) zzs = t;
    }
    __syncthreads();

    // dists: one code per thread
    {
        float dot = 0.f, cc = 0.f;
        const float* __restrict__ cp = cb + (size_t)tid * 128;
        #pragma unroll 8
        for (int k = 0; k < 128; ++k) {
            float v = cp[k];
            dot = fmaf(ze[k], v, dot);
            cc  = fmaf(v, v, cc);
        }
        red_d[tid] = zzs - 2.f * dot + cc;
        red_i[tid] = tid;
    }
    __syncthreads();

    // argmin (tie -> lowest index, = np.argmin)
    for (int sft = 256; sft >= 1; sft >>= 1) {
        if (tid < sft) {
            float da = red_d[tid], db = red_d[tid + sft];
            int   ia = red_i[tid], ib = red_i[tid + sft];
            if (db < da || (db == da && ib < ia)) { red_d[tid] = db; red_i[tid] = ib; }
        }
        __syncthreads();
    }
    const int bc = red_i[0];

    if (tid < 128) {
        float zq  = cb[(size_t)bc * 128 + tid];
        float zev = ze[tid];
        out[b * 128 + tid] = zev + (zq - zev);  // z_q_st
    }
    if (tid == 0) out[16386 + b] = (float)bc;   // index as float
}

// Deterministic single-block loss reduction.
__global__ __launch_bounds__(256) void k3_loss(const float* __restrict__ cb,
                                               float* __restrict__ out)
{
    const int tid = threadIdx.x;
    __shared__ float red[256];
    float p = 0.f;
    for (int i = tid; i < 8192; i += 256) {
        const int b = i >> 7, k = i & 127;
        const int idx = (int)out[16386 + b];
        float d = cb[(size_t)idx * 128 + k] - out[8192 + i];
        p = fmaf(d, d, p);
    }
    red[tid] = p;
    __syncthreads();
    for (int sft = 128; sft >= 1; sft >>= 1) {
        if (tid < sft) red[tid] += red[tid + sft];
        __syncthreads();
    }
    if (tid == 0) {
        float m = red[0] / 8192.f;
        out[16384] = m;   // codebook_loss
        out[16385] = m;   // commitment_loss (identical numerically)
    }
}

extern "C" void kernel_launch(void* const* d_in, const int* in_sizes, int n_in,
                              void* d_out, int out_size, void* d_ws, size_t ws_size,
                              hipStream_t stream) {
    const float* x  = (const float*)d_in[0];
    const float* s  = (const float*)d_in[1];
    const float* e  = (const float*)d_in[2];
    const float* W1 = (const float*)d_in[3];
    const float* b1 = (const float*)d_in[4];
    const float* W2 = (const float*)d_in[5];
    const float* b2 = (const float*)d_in[6];
    const float* W3 = (const float*)d_in[7];
    const float* b3 = (const float*)d_in[8];
    const float* W4 = (const float*)d_in[9];
    const float* b4 = (const float*)d_in[10];
    const float* cb = (const float*)d_in[11];
    float* out = (float*)d_out;

    unsigned* keys = (unsigned*)d_ws;                 // 8192 u32

    k0_init<<<32, 256, 0, stream>>>(keys);
    k1_pointfeat<<<2048, 256, 0, stream>>>(x, s, W1, b1, W2, keys);
    k2_head<<<64, 512, 0, stream>>>(keys, b2, e, W3, b3, W4, b4, cb, out);
    k3_loss<<<1, 256, 0, stream>>>(cb, out);
}

// Round 3
// 80.786 us; speedup vs baseline: 2.3890x; 2.2437x over previous
//
#include <hip/hip_runtime.h>

#define TEXTD 512

typedef unsigned short u16;
typedef __attribute__((ext_vector_type(8))) short s16x8;    // 8 bf16 = 4 VGPR
typedef __attribute__((ext_vector_type(16))) float f32x16;  // MFMA 32x32 C/D

__device__ __forceinline__ unsigned mono(float f) {
    unsigned u = __float_as_uint(f);
    return (u & 0x80000000u) ? ~u : (u | 0x80000000u);
}
__device__ __forceinline__ float unmono(unsigned k) {
    return __uint_as_float((k & 0x80000000u) ? (k & 0x7fffffffu) : ~k);
}
// bf16 RNE via bit ops (no NaN inputs here)
__device__ __forceinline__ u16 f2bf(float f) {
    unsigned u = __float_as_uint(f);
    return (u16)((u + 0x7FFFu + ((u >> 16) & 1u)) >> 16);
}
__device__ __forceinline__ float bf2f(u16 h) {
    return __uint_as_float(((unsigned)h) << 16);
}

__global__ void k0_init(unsigned* __restrict__ keys) {
    int idx = blockIdx.x * 256 + threadIdx.x;
    if (idx < 8192) keys[idx] = 0u;   // mono-space -inf
}

// Split-bf16 MFMA point-feature kernel.
// 1024 blocks x 128 threads; each wave independently handles 4 groups of 64
// consecutive points (256 pts/wave, all in one batch). Layer1 (4->64) in fp32
// VALU; layer2 (64x128) via 3-pass split-bf16 mfma_f32_32x32x16_bf16 with W2
// hi/lo fragments resident in VGPRs. Max-pool folded out of C fragments
// (C col = feature, rows = points). b2 folded into k2.
__global__ __launch_bounds__(128, 2) void k1_pointfeat(
    const float* __restrict__ x, const float* __restrict__ s,
    const float* __restrict__ W1, const float* __restrict__ b1,
    const float* __restrict__ W2, unsigned* __restrict__ keys)
{
    // per-wave private slices; rows padded 64->72 bf16 (144B) so row stride
    // rotates bank-quads (9 mod 8 = 1): conflict-free b128 read/write.
    __shared__ u16 lds[2][2][64][72];
    const int tid  = threadIdx.x;
    const int lane = tid & 63;
    const int wid  = tid >> 6;
    const int cl   = lane & 31;   // MFMA row/col lane id
    const int kg   = lane >> 5;   // MFMA k-group

    u16 (*Hh)[72] = lds[wid][0];
    u16 (*Hl)[72] = lds[wid][1];

    const int waveId = blockIdx.x * 2 + wid;   // 2048 waves
    const int p0 = waveId * 256;               // 4 groups x 64 points
    const int b  = p0 >> 13;                   // 8192 points per batch

    // ---- W2 split fragments (B-frags), resident in VGPRs ----
    // B[k][n] frag: lane holds k = s*16 + kg*8 + j, n = nt*32 + cl
    s16x8 wh[4][4], wl[4][4];                  // [nt][s]
    #pragma unroll
    for (int nt = 0; nt < 4; ++nt)
        #pragma unroll
        for (int sl = 0; sl < 4; ++sl)
            #pragma unroll
            for (int j = 0; j < 8; ++j) {
                float f = W2[(sl * 16 + kg * 8 + j) * 128 + nt * 32 + cl];
                u16 hb = f2bf(f);
                u16 lb = f2bf(f - bf2f(hb));
                wh[nt][sl][j] = (short)hb;
                wl[nt][sl][j] = (short)lb;
            }

    float rmax[4] = {-3.402823466e38f, -3.402823466e38f,
                     -3.402823466e38f, -3.402823466e38f};

    #pragma unroll 1
    for (int g = 0; g < 4; ++g) {
        const int gp = p0 + g * 64 + lane;     // lane = point
        const float px = x[(size_t)gp * 3 + 0];
        const float py = x[(size_t)gp * 3 + 1];
        const float pz = x[(size_t)gp * 3 + 2];
        const float pw = s[gp];

        // layer1 + split + LDS write, 8 features per chunk
        #pragma unroll
        for (int c = 0; c < 8; ++c) {
            s16x8 hv, lv;
            #pragma unroll
            for (int j = 0; j < 8; ++j) {
                const int k = c * 8 + j;
                float a = fmaf(px, W1[k],
                          fmaf(py, W1[64 + k],
                          fmaf(pz, W1[128 + k],
                          fmaf(pw, W1[192 + k], b1[k]))));
                a = a > 0.f ? a : 0.f;
                u16 hb = f2bf(a);
                u16 lb = f2bf(a - bf2f(hb));
                hv[j] = (short)hb;
                lv[j] = (short)lb;
            }
            *(s16x8*)&Hh[lane][c * 8] = hv;
            *(s16x8*)&Hl[lane][c * 8] = lv;
        }

        // MFMA: 2 M-tiles x 4 N-tiles x 4 K-slabs x 3 passes
        #pragma unroll
        for (int m = 0; m < 2; ++m) {
            f32x16 acc[4] = {};
            #pragma unroll
            for (int sl = 0; sl < 4; ++sl) {
                const s16x8 ahi = *(const s16x8*)&Hh[m * 32 + cl][sl * 16 + kg * 8];
                const s16x8 alo = *(const s16x8*)&Hl[m * 32 + cl][sl * 16 + kg * 8];
                #pragma unroll
                for (int nt = 0; nt < 4; ++nt)
                    acc[nt] = __builtin_amdgcn_mfma_f32_32x32x16_bf16(ahi, wh[nt][sl], acc[nt], 0, 0, 0);
                #pragma unroll
                for (int nt = 0; nt < 4; ++nt)
                    acc[nt] = __builtin_amdgcn_mfma_f32_32x32x16_bf16(ahi, wl[nt][sl], acc[nt], 0, 0, 0);
                #pragma unroll
                for (int nt = 0; nt < 4; ++nt)
                    acc[nt] = __builtin_amdgcn_mfma_f32_32x32x16_bf16(alo, wh[nt][sl], acc[nt], 0, 0, 0);
            }
            // C layout: col(feature) = cl, rows(points) spread over regs
            #pragma unroll
            for (int nt = 0; nt < 4; ++nt)
                #pragma unroll
                for (int r = 0; r < 16; ++r)
                    rmax[nt] = fmaxf(rmax[nt], acc[nt][r]);
        }
    }

    // lanes l and l+32 hold the same feature column
    #pragma unroll
    for (int nt = 0; nt < 4; ++nt)
        rmax[nt] = fmaxf(rmax[nt], __shfl_xor(rmax[nt], 32, 64));
    if (lane < 32) {
        #pragma unroll
        for (int nt = 0; nt < 4; ++nt)
            atomicMax(&keys[b * 128 + nt * 32 + cl], mono(rmax[nt]));
    }
}

// One block per batch: head MLP + VQ. Adds the folded-out b2.
__global__ __launch_bounds__(512) void k2_head(
    const unsigned* __restrict__ keys, const float* __restrict__ b2,
    const float* __restrict__ e,
    const float* __restrict__ W3, const float* __restrict__ b3,
    const float* __restrict__ W4, const float* __restrict__ b4,
    const float* __restrict__ cb, float* __restrict__ out)
{
    const int b = blockIdx.x, tid = threadIdx.x;
    __shared__ float comb[640];
    __shared__ float psum[512];
    __shared__ float hid[256];
    __shared__ float ze[128];
    __shared__ float red_d[512];
    __shared__ int   red_i[512];
    __shared__ float zzs;

    if (tid < 128) comb[tid] = unmono(keys[b * 128 + tid]) + b2[tid];
    comb[128 + tid] = e[b * TEXTD + tid];
    __syncthreads();

    {
        const int u = tid & 255, part = tid >> 8;
        float a = part ? 0.f : b3[u];
        const int i0 = part * 320;
        for (int i = i0; i < i0 + 320; ++i) a = fmaf(comb[i], W3[i * 256 + u], a);
        psum[part * 256 + u] = a;
    }
    __syncthreads();
    if (tid < 256) {
        float hv = psum[tid] + psum[256 + tid];
        hid[tid] = hv > 0.f ? hv : 0.f;
    }
    __syncthreads();

    if (tid < 128) {
        float a = b4[tid];
        for (int i = 0; i < 256; ++i) a = fmaf(hid[i], W4[i * 128 + tid], a);
        ze[tid] = a;
        out[8192 + b * 128 + tid] = a;
    }
    __syncthreads();

    if (tid < 64) {
        float t = ze[tid] * ze[tid] + ze[tid + 64] * ze[tid + 64];
        #pragma unroll
        for (int d = 1; d < 64; d <<= 1) t += __shfl_xor(t, d, 64);
        if (tid == 0) zzs = t;
    }
    __syncthreads();

    {
        float dot = 0.f, cc = 0.f;
        const float* __restrict__ cp = cb + (size_t)tid * 128;
        #pragma unroll 8
        for (int k = 0; k < 128; ++k) {
            float v = cp[k];
            dot = fmaf(ze[k], v, dot);
            cc  = fmaf(v, v, cc);
        }
        red_d[tid] = zzs - 2.f * dot + cc;
        red_i[tid] = tid;
    }
    __syncthreads();

    for (int sft = 256; sft >= 1; sft >>= 1) {
        if (tid < sft) {
            float da = red_d[tid], db = red_d[tid + sft];
            int   ia = red_i[tid], ib = red_i[tid + sft];
            if (db < da || (db == da && ib < ia)) { red_d[tid] = db; red_i[tid] = ib; }
        }
        __syncthreads();
    }
    const int bc = red_i[0];

    if (tid < 128) {
        float zq  = cb[(size_t)bc * 128 + tid];
        float zev = ze[tid];
        out[b * 128 + tid] = zev + (zq - zev);
    }
    if (tid == 0) out[16386 + b] = (float)bc;
}

__global__ __launch_bounds__(256) void k3_loss(const float* __restrict__ cb,
                                               float* __restrict__ out)
{
    const int tid = threadIdx.x;
    __shared__ float red[256];
    float p = 0.f;
    for (int i = tid; i < 8192; i += 256) {
        const int b = i >> 7, k = i & 127;
        const int idx = (int)out[16386 + b];
        float d = cb[(size_t)idx * 128 + k] - out[8192 + i];
        p = fmaf(d, d, p);
    }
    red[tid] = p;
    __syncthreads();
    for (int sft = 128; sft >= 1; sft >>= 1) {
        if (tid < sft) red[tid] += red[tid + sft];
        __syncthreads();
    }
    if (tid == 0) {
        float m = red[0] / 8192.f;
        out[16384] = m;
        out[16385] = m;
    }
}

extern "C" void kernel_launch(void* const* d_in, const int* in_sizes, int n_in,
                              void* d_out, int out_size, void* d_ws, size_t ws_size,
                              hipStream_t stream) {
    const float* x  = (const float*)d_in[0];
    const float* s  = (const float*)d_in[1];
    const float* e  = (const float*)d_in[2];
    const float* W1 = (const float*)d_in[3];
    const float* b1 = (const float*)d_in[4];
    const float* W2 = (const float*)d_in[5];
    const float* b2 = (const float*)d_in[6];
    const float* W3 = (const float*)d_in[7];
    const float* b3 = (const float*)d_in[8];
    const float* W4 = (const float*)d_in[9];
    const float* b4 = (const float*)d_in[10];
    const float* cb = (const float*)d_in[11];
    float* out = (float*)d_out;

    unsigned* keys = (unsigned*)d_ws;   // 8192 u32

    k0_init<<<32, 256, 0, stream>>>(keys);
    k1_pointfeat<<<1024, 128, 0, stream>>>(x, s, W1, b1, W2, keys);
    k2_head<<<64, 512, 0, stream>>>(keys, b2, e, W3, b3, W4, b4, cb, out);
    k3_loss<<<1, 256, 0, stream>>>(cb, out);
}